// Round 7
// baseline (307.155 us; speedup 1.0000x reference)
//
#include <hip/hip_runtime.h>

// Problem constants
#define B_  4
#define S_  2048
#define E_  1024
#define H_  16
#define DK_ 64
#define M_  (B_*S_)   // 8192

typedef __attribute__((ext_vector_type(8)))  short short8;   // 8 bf16 (4 VGPRs)
typedef __attribute__((ext_vector_type(4)))  float f32x4;
typedef __attribute__((ext_vector_type(16))) float f32x16;   // 32x32 MFMA accumulator

#define QSCALE 0.18033688f   // 0.125 * log2(e): folded into Q so p = exp2(score)

// fp32 -> bf16 round-to-nearest-even
__device__ __forceinline__ unsigned short f2b(float f) {
    union { float f; unsigned u; } v; v.f = f;
    unsigned u = v.u;
    return (unsigned short)((u + 0x7fffu + ((u >> 16) & 1u)) >> 16);
}

// async global->LDS, 16 bytes/lane. LDS dest = wave-uniform base + lane*16.
__device__ __forceinline__ void gload_lds16(const unsigned short* g, unsigned short* l) {
    __builtin_amdgcn_global_load_lds((const __attribute__((address_space(1))) void*)g,
                                     (__attribute__((address_space(3))) void*)l, 16, 0, 0);
}

// One launch for all fp32->bf16 converts: x (M*E) then Wq,Wk,Wv,Wo (E*E each).
#define XN4 (M_*E_/4)
#define WN4 (E_*E_/4)
__global__ __launch_bounds__(256) void cvt_all(
    const float* __restrict__ x,
    const float* __restrict__ w0, const float* __restrict__ w1,
    const float* __restrict__ w2, const float* __restrict__ w3,
    unsigned short* __restrict__ xb, unsigned short* __restrict__ wb,
    unsigned short* __restrict__ wob) {
    int i = blockIdx.x * 256 + threadIdx.x;
    const float* src;
    unsigned short* dst;
    int idx;
    if (i < XN4) { src = x; dst = xb; idx = i; }
    else {
        int j = i - XN4;
        int z = j >> 18;              // / WN4 (2^18)
        idx = j & (WN4 - 1);
        src = (z == 0) ? w0 : (z == 1) ? w1 : (z == 2) ? w2 : w3;
        dst = (z < 3) ? wb + (size_t)z * E_ * E_ : wob;
    }
    float4 f = ((const float4*)src)[idx];
    ushort4 o;
    o.x = f2b(f.x); o.y = f2b(f.y); o.z = f2b(f.z); o.w = f2b(f.w);
    ((ushort4*)dst)[idx] = o;
}

// ---------------------------------------------------------------------------
// Shared 128x128 K-loop (m97 structure). FLIP=true computes C^T (operands
// swapped: A- and B-frag lane layouts are identical for bf16 MFMA).
//   FLIP=false: acc[i][j] C-layout: col=m(i-tile), regs=4 consecutive m... no:
//     col = m-within-16, row(quad*4+r) = m... standard: col=n? We orient:
//     normal:  C[m][n]: col = n, regs = consecutive m  (m = wm+i*16+quad*4+r)
//     flipped: C[n][m]: col = m, regs = consecutive n  (n = wn+j*16+quad*4+r)
// ---------------------------------------------------------------------------
template<bool FLIP>
__device__ __forceinline__ void gemm_kloop(
    const unsigned short* __restrict__ Ag, const unsigned short* __restrict__ Bg,
    unsigned short* As, unsigned short* Bs,
    int m0, int n0, int w, int lane, f32x4 acc[4][4])
{
    const int quad = lane >> 4, col = lane & 15;
    const int wm = (w & 1) * 64, wn = (w >> 1) * 64;
    const int srow = lane >> 3, schunk = (lane & 7) * 8;
    for (int k0 = 0; k0 < E_; k0 += 64) {
        #pragma unroll
        for (int c = 0; c < 4; c++) {
            int row = w*32 + c*8 + srow;
            gload_lds16(&Ag[(size_t)(m0+row)*E_ + k0 + schunk], &As[(w*32 + c*8)*64]);
            gload_lds16(&Bg[(size_t)(n0+row)*E_ + k0 + schunk], &Bs[(w*32 + c*8)*64]);
        }
        __syncthreads();
        #pragma unroll
        for (int kk = 0; kk < 64; kk += 32) {
            short8 a[4], b[4];
            #pragma unroll
            for (int i = 0; i < 4; i++)
                a[i] = *(const short8*)&As[(wm + i*16 + col)*64 + kk + quad*8];
            #pragma unroll
            for (int j = 0; j < 4; j++)
                b[j] = *(const short8*)&Bs[(wn + j*16 + col)*64 + kk + quad*8];
            #pragma unroll
            for (int i = 0; i < 4; i++)
                #pragma unroll
                for (int j = 0; j < 4; j++)
                    acc[i][j] = FLIP
                      ? __builtin_amdgcn_mfma_f32_16x16x32_bf16(b[j], a[i], acc[i][j], 0, 0, 0)
                      : __builtin_amdgcn_mfma_f32_16x16x32_bf16(a[i], b[j], acc[i][j], 0, 0, 0);
        }
        __syncthreads();
    }
}

// y = x @ W_z.T ; q/k = cos(y+theta) -> [bh][s][d]; v -> cos -> [bh][d][s].
// No epilogue LDS: C^T orientation gives reg-contiguous d for q/k (b64 direct
// stores); normal orientation gives reg-contiguous s for vtb.
__global__ __launch_bounds__(256) void gemm_qkv(
    const unsigned short* __restrict__ xb,   // [M][E]
    const unsigned short* __restrict__ Wb,   // [3][E][E]
    const float* __restrict__ theta,         // [64]
    unsigned short* __restrict__ qb,         // [B*H][S][DK]  (q pre-scaled)
    unsigned short* __restrict__ kb,         // [B*H][S][DK]
    unsigned short* __restrict__ vtb)        // [B*H][DK][S]
{
    __shared__ unsigned short As[128*64];
    __shared__ unsigned short Bs[128*64];
    const int tid = threadIdx.x;
    const int w = tid >> 6, lane = tid & 63, quad = lane >> 4, col = lane & 15;
    const int wm = (w & 1) * 64, wn = (w >> 1) * 64;
    const int m0 = blockIdx.x * 128, n0 = blockIdx.y * 128, z = blockIdx.z;
    const unsigned short* Wz = Wb + (size_t)z * E_ * E_;
    const int bblk = m0 >> 11, sbase = m0 & (S_-1);

    f32x4 acc[4][4] = {};
    if (z != 2) {
        gemm_kloop<true>(xb, Wz, As, Bs, m0, n0, w, lane, acc);
        const float qs = (z == 0) ? QSCALE : 1.0f;
        unsigned short* dst = (z == 0) ? qb : kb;
        #pragma unroll
        for (int j = 0; j < 4; j++) {
            int nb = wn + j*16 + quad*4;                 // n-base of the 4 regs
            int h = (n0 + nb) >> 6, d0 = nb & 63;
            float4 th = *(const float4*)&theta[d0];
            #pragma unroll
            for (int i = 0; i < 4; i++) {
                int s = sbase + wm + i*16 + col;
                ushort4 o;
                o.x = f2b(__cosf(acc[i][j][0] + th.x) * qs);
                o.y = f2b(__cosf(acc[i][j][1] + th.y) * qs);
                o.z = f2b(__cosf(acc[i][j][2] + th.z) * qs);
                o.w = f2b(__cosf(acc[i][j][3] + th.w) * qs);
                *(ushort4*)&dst[((size_t)(bblk*H_ + h)*S_ + s)*DK_ + d0] = o;
            }
        }
    } else {
        gemm_kloop<false>(xb, Wz, As, Bs, m0, n0, w, lane, acc);
        #pragma unroll
        for (int j = 0; j < 4; j++) {
            int n = n0 + wn + j*16 + col;
            int h = n >> 6, d = n & 63;
            float th = theta[d];
            #pragma unroll
            for (int i = 0; i < 4; i++) {
                int s0 = sbase + wm + i*16 + quad*4;     // 4 consecutive s
                ushort4 o;
                o.x = f2b(__cosf(acc[i][j][0] + th));
                o.y = f2b(__cosf(acc[i][j][1] + th));
                o.z = f2b(__cosf(acc[i][j][2] + th));
                o.w = f2b(__cosf(acc[i][j][3] + th));
                *(ushort4*)&vtb[((size_t)(bblk*H_ + h)*DK_ + d)*S_ + s0] = o;
            }
        }
    }
}

// out = ctx @ Wo.T, fp32. C^T orientation -> reg-contiguous n -> float4 stores.
__global__ __launch_bounds__(256) void gemm_out(
    const unsigned short* __restrict__ ctx,  // [M][E]
    const unsigned short* __restrict__ Wob,  // [E][E]
    float* __restrict__ out)                 // [M][E] fp32
{
    __shared__ unsigned short As[128*64];
    __shared__ unsigned short Bs[128*64];
    const int tid = threadIdx.x;
    const int w = tid >> 6, lane = tid & 63, quad = lane >> 4, col = lane & 15;
    const int wm = (w & 1) * 64, wn = (w >> 1) * 64;
    const int m0 = blockIdx.x * 128, n0 = blockIdx.y * 128;

    f32x4 acc[4][4] = {};
    gemm_kloop<true>(ctx, Wob, As, Bs, m0, n0, w, lane, acc);
    #pragma unroll
    for (int j = 0; j < 4; j++) {
        int nb = n0 + wn + j*16 + quad*4;
        #pragma unroll
        for (int i = 0; i < 4; i++) {
            int m = m0 + wm + i*16 + col;
            *(f32x4*)&out[(size_t)m*E_ + nb] = acc[i][j];
        }
    }
}

// ---------------------------------------------------------------------------
// Flash attention (round-5 shape: 32 q/wave, 128 q/block, grid 16x64):
// S^T formulation, 32x32x16 MFMA, shuffle-based C->A transform, no P LDS.
// l by VALU rsum + end shuffles (no l-MFMA). p=exp2(score), Q pre-scaled.
// ---------------------------------------------------------------------------
#define LPK 72   // padded LDS row stride (elements)

__global__ __launch_bounds__(256, 4) void flash_attn(
    const unsigned short* __restrict__ qb,   // pre-scaled by QSCALE
    const unsigned short* __restrict__ kb,
    const unsigned short* __restrict__ vtb,
    unsigned short* __restrict__ ctx)        // [M][E] bf16
{
    __shared__ unsigned short Kt[64*LPK];    // [key][d]
    __shared__ unsigned short Vt[64*LPK];    // [d][key]
    const int tid = threadIdx.x;
    const int w = tid >> 6, lane = tid & 63, col = lane & 31, half = lane >> 5;
    const int q0 = blockIdx.x * 128;
    const int bh = blockIdx.y;

    union U8 { unsigned u[4]; short8 s8; };

    short8 qf[4];
    {
        const unsigned short* qrow = qb + ((size_t)bh*S_ + q0 + w*32 + col)*DK_;
        #pragma unroll
        for (int c = 0; c < 4; c++)
            qf[c] = *(const short8*)&qrow[c*16 + half*8];
    }

    float rsum = 0.f;
    f32x16 oacc[2] = {};

    for (int kt = 0; kt < S_; kt += 64) {
        __syncthreads();
        for (int i = tid; i < 512; i += 256) {
            int row = i >> 3, c8 = (i & 7) * 8;
            *(int4*)&Kt[row*LPK + c8] = *(const int4*)&kb [((size_t)bh*S_  + kt + row)*DK_ + c8];
            *(int4*)&Vt[row*LPK + c8] = *(const int4*)&vtb[((size_t)bh*DK_ + row)*S_ + kt + c8];
        }
        __syncthreads();

        #pragma unroll
        for (int t = 0; t < 2; t++) {
            // S^T = K.Q^T over this 32-key tile
            f32x16 sacc = {};
            #pragma unroll
            for (int c = 0; c < 4; c++) {
                short8 kf = *(const short8*)&Kt[(t*32 + col)*LPK + c*16 + half*8];
                sacc = __builtin_amdgcn_mfma_f32_32x32x16_bf16(kf, qf[c], sacc, 0, 0, 0);
            }
            // p = exp2(score); pack pairs via v_perm (hi-16 truncation)
            unsigned pk[4][2];
            #pragma unroll
            for (int rg = 0; rg < 4; rg++) {
                float p0 = __builtin_amdgcn_exp2f(sacc[rg*4+0]);
                float p1 = __builtin_amdgcn_exp2f(sacc[rg*4+1]);
                float p2 = __builtin_amdgcn_exp2f(sacc[rg*4+2]);
                float p3 = __builtin_amdgcn_exp2f(sacc[rg*4+3]);
                rsum += (p0 + p1) + (p2 + p3);
                pk[rg][0] = __builtin_amdgcn_perm(__float_as_uint(p1), __float_as_uint(p0), 0x07060302u);
                pk[rg][1] = __builtin_amdgcn_perm(__float_as_uint(p3), __float_as_uint(p2), 0x07060302u);
            }
            // PV over the two 16-key chunks (C->A transform via one shfl pair)
            #pragma unroll
            for (int kc = 0; kc < 2; kc++) {
                const int lo = 2*kc, hi = 2*kc + 1;
                unsigned t0 = half ? pk[lo][0] : pk[hi][0];
                unsigned t1 = half ? pk[lo][1] : pk[hi][1];
                unsigned r0 = __shfl_xor((int)t0, 32);
                unsigned r1 = __shfl_xor((int)t1, 32);
                U8 pa;
                pa.u[0] = half ? r0 : pk[lo][0];
                pa.u[1] = half ? r1 : pk[lo][1];
                pa.u[2] = half ? pk[hi][0] : r0;
                pa.u[3] = half ? pk[hi][1] : r1;
                #pragma unroll
                for (int dt = 0; dt < 2; dt++) {
                    short8 vf = *(const short8*)&Vt[(dt*32 + col)*LPK + t*32 + kc*16 + half*8];
                    oacc[dt] = __builtin_amdgcn_mfma_f32_32x32x16_bf16(pa.s8, vf, oacc[dt], 0, 0, 0);
                }
            }
        }
    }

    // epilogue: l(q=col) = both halves' rsum; redistribute inv to C rows
    const int b = bh >> 4, h = bh & 15;
    float l = rsum + __shfl_xor(rsum, 32);
    float inv = 1.0f / l;                    // lane holds inv for q = col
    #pragma unroll
    for (int rg = 0; rg < 4; rg++)
        #pragma unroll
        for (int rr = 0; rr < 4; rr++) {
            int row = rr + rg*8 + half*4;
            float invr = __shfl(inv, row);
            int s = q0 + w*32 + row;
            size_t rowoff = ((size_t)(b*S_ + s))*E_ + h*64;
            #pragma unroll
            for (int dt = 0; dt < 2; dt++)
                ctx[rowoff + dt*32 + col] = f2b(oacc[dt][rg*4 + rr] * invr);
        }
}

extern "C" void kernel_launch(void* const* d_in, const int* in_sizes, int n_in,
                              void* d_out, int out_size, void* d_ws, size_t ws_size,
                              hipStream_t stream) {
    (void)in_sizes; (void)n_in; (void)out_size; (void)ws_size;
    const float* x     = (const float*)d_in[0];
    const float* Wq    = (const float*)d_in[1];
    const float* Wk    = (const float*)d_in[2];
    const float* Wv    = (const float*)d_in[3];
    const float* Wo    = (const float*)d_in[4];
    const float* theta = (const float*)d_in[5];
    float* out = (float*)d_out;

    unsigned short* ws  = (unsigned short*)d_ws;
    unsigned short* xb  = ws;                                    // M*E
    unsigned short* Wb  = xb  + (size_t)M_*E_;                   // 3*E*E
    unsigned short* Wob = Wb  + (size_t)3*E_*E_;                 // E*E
    unsigned short* qb  = Wob + (size_t)E_*E_;
    unsigned short* kb  = qb  + (size_t)B_*H_*S_*DK_;
    unsigned short* vtb = kb  + (size_t)B_*H_*S_*DK_;
    unsigned short* ctx = xb;                                    // alias (xb dead after gemm_qkv)

    cvt_all<<<(XN4 + 4*WN4)/256, 256, 0, stream>>>(x, Wq, Wk, Wv, Wo, xb, Wb, Wob);

    gemm_qkv<<<dim3(M_/128, E_/128, 3), 256, 0, stream>>>(xb, Wb, theta, qb, kb, vtb);
    flash_attn<<<dim3(S_/128, B_*H_), 256, 0, stream>>>(qb, kb, vtb, ctx);
    gemm_out<<<dim3(M_/128, E_/128), 256, 0, stream>>>(ctx, Wob, out);
}

// Round 8
// 290.884 us; speedup vs baseline: 1.0559x; 1.0559x over previous
//
#include <hip/hip_runtime.h>

// Problem constants
#define B_  4
#define S_  2048
#define E_  1024
#define H_  16
#define DK_ 64
#define M_  (B_*S_)   // 8192

typedef __attribute__((ext_vector_type(8)))  short short8;   // 8 bf16 (4 VGPRs)
typedef __attribute__((ext_vector_type(4)))  float f32x4;
typedef __attribute__((ext_vector_type(16))) float f32x16;   // 32x32 MFMA accumulator

#define QSCALE 0.18033688f   // 0.125 * log2(e): folded into Q so p = exp2(score)

// fp32 -> bf16 round-to-nearest-even
__device__ __forceinline__ unsigned short f2b(float f) {
    union { float f; unsigned u; } v; v.f = f;
    unsigned u = v.u;
    return (unsigned short)((u + 0x7fffu + ((u >> 16) & 1u)) >> 16);
}

// async global->LDS, 16 bytes/lane. LDS dest = wave-uniform base + lane*16.
__device__ __forceinline__ void gload_lds16(const unsigned short* g, unsigned short* l) {
    __builtin_amdgcn_global_load_lds((const __attribute__((address_space(1))) void*)g,
                                     (__attribute__((address_space(3))) void*)l, 16, 0, 0);
}

// One launch for all fp32->bf16 converts: x (M*E) then Wq,Wk,Wv,Wo (E*E each).
#define XN4 (M_*E_/4)
#define WN4 (E_*E_/4)
__global__ __launch_bounds__(256) void cvt_all(
    const float* __restrict__ x,
    const float* __restrict__ w0, const float* __restrict__ w1,
    const float* __restrict__ w2, const float* __restrict__ w3,
    unsigned short* __restrict__ xb, unsigned short* __restrict__ wb,
    unsigned short* __restrict__ wob) {
    int i = blockIdx.x * 256 + threadIdx.x;
    const float* src;
    unsigned short* dst;
    int idx;
    if (i < XN4) { src = x; dst = xb; idx = i; }
    else {
        int j = i - XN4;
        int z = j >> 18;              // / WN4 (2^18)
        idx = j & (WN4 - 1);
        src = (z == 0) ? w0 : (z == 1) ? w1 : (z == 2) ? w2 : w3;
        dst = (z < 3) ? wb + (size_t)z * E_ * E_ : wob;
    }
    float4 f = ((const float4*)src)[idx];
    ushort4 o;
    o.x = f2b(f.x); o.y = f2b(f.y); o.z = f2b(f.z); o.w = f2b(f.w);
    ((ushort4*)dst)[idx] = o;
}

// ---------------------------------------------------------------------------
// 128x128-tile GEMM (m97 structure). All epilogues transpose through LDS for
// coalesced b128 global stores. q output pre-scaled by QSCALE.
// ---------------------------------------------------------------------------
__global__ __launch_bounds__(256) void gemm_qkv(
    const unsigned short* __restrict__ xb,   // [M][E]
    const unsigned short* __restrict__ Wb,   // [3][E][E]
    const float* __restrict__ theta,         // [64]
    unsigned short* __restrict__ qb,         // [B*H][S][DK]  (q pre-scaled)
    unsigned short* __restrict__ kb,         // [B*H][S][DK]
    unsigned short* __restrict__ vtb)        // [B*H][DK][S]
{
    __shared__ unsigned short smem[128*144];            // 36864 B
    unsigned short* As = smem;                          // [128][64]
    unsigned short* Bs = smem + 128*64;
    const int tid = threadIdx.x;
    const int w = tid >> 6, lane = tid & 63, quad = lane >> 4, col = lane & 15;
    const int wm = (w & 1) * 64, wn = (w >> 1) * 64;
    const int m0 = blockIdx.x * 128, n0 = blockIdx.y * 128, z = blockIdx.z;
    const unsigned short* Wz = Wb + (size_t)z * E_ * E_;
    const int srow = lane >> 3, schunk = (lane & 7) * 8;

    f32x4 acc[4][4] = {};
    for (int k0 = 0; k0 < E_; k0 += 64) {
        #pragma unroll
        for (int c = 0; c < 4; c++) {
            int row = w*32 + c*8 + srow;
            gload_lds16(&xb[(size_t)(m0+row)*E_ + k0 + schunk], &As[(w*32 + c*8)*64]);
            gload_lds16(&Wz[(size_t)(n0+row)*E_ + k0 + schunk], &Bs[(w*32 + c*8)*64]);
        }
        __syncthreads();
        #pragma unroll
        for (int kk = 0; kk < 64; kk += 32) {
            short8 a[4], b[4];
            #pragma unroll
            for (int i = 0; i < 4; i++)
                a[i] = *(const short8*)&As[(wm + i*16 + col)*64 + kk + quad*8];
            #pragma unroll
            for (int j = 0; j < 4; j++)
                b[j] = *(const short8*)&Bs[(wn + j*16 + col)*64 + kk + quad*8];
            #pragma unroll
            for (int i = 0; i < 4; i++)
                #pragma unroll
                for (int j = 0; j < 4; j++)
                    acc[i][j] = __builtin_amdgcn_mfma_f32_16x16x32_bf16(a[i], b[j], acc[i][j], 0, 0, 0);
        }
        __syncthreads();
    }

    const int bblk = m0 >> 11;            // batch index (tile never crosses S)
    const int sbase = m0 & (S_-1);

    if (z != 2) {
        const float qs = (z == 0) ? QSCALE : 1.0f;
        // C -> smem[m][n] (stride 144), quad-XOR swizzle on n (16-elt granularity)
        #pragma unroll
        for (int j = 0; j < 4; j++) {
            int nl = wn + j*16 + col;
            float th = theta[(n0 + nl) & 63];
            #pragma unroll
            for (int i = 0; i < 4; i++)
                #pragma unroll
                for (int r = 0; r < 4; r++) {
                    int ml = wm + i*16 + quad*4 + r;
                    int nls = nl ^ (((ml >> 2) & 3) << 4);
                    smem[ml*144 + nls] = f2b(__cosf(acc[i][j][r] + th) * qs);
                }
        }
        __syncthreads();
        unsigned short* dst = (z == 0) ? qb : kb;
        const int h0 = n0 >> 6;
        #pragma unroll
        for (int k = 0; k < 8; k++) {
            int idx = k*256 + tid;
            int chunk = idx & 7, seg = idx >> 3;
            int ml = seg >> 1, hh = seg & 1;
            int ch = chunk ^ (((ml >> 2) & 3) << 1);     // de-swizzle (8-elt chunks)
            int4 val = *(const int4*)&smem[ml*144 + hh*64 + ch*8];
            size_t g = ((size_t)(bblk*H_ + h0 + hh)*S_ + sbase + ml)*DK_ + chunk*8;
            *(int4*)&dst[g] = val;
        }
    } else {
        // V: transpose tile (n-major) -> vtb[bh][d][s] coalesced rows
        #pragma unroll
        for (int j = 0; j < 4; j++) {
            int nl = wn + j*16 + col;
            float th = theta[(n0 + nl) & 63];
            #pragma unroll
            for (int i = 0; i < 4; i++)
                #pragma unroll
                for (int r = 0; r < 4; r++)
                    smem[nl*136 + wm + i*16 + quad*4 + r] = f2b(__cosf(acc[i][j][r] + th));
        }
        __syncthreads();
        int row = tid >> 1, halfm = (tid & 1) * 64;     // 2 threads per n-row
        int n = n0 + row, h = n >> 6, d = n & 63;
        size_t base = ((size_t)(bblk*H_ + h)*DK_ + d)*S_ + sbase + halfm;
        #pragma unroll
        for (int k = 0; k < 8; k++)
            *(int4*)&vtb[base + k*8] = *(const int4*)&smem[row*136 + halfm + k*8];
    }
}

// out = ctx @ Wo.T, fp32 output
__global__ __launch_bounds__(256) void gemm_out(
    const unsigned short* __restrict__ ctx,  // [M][E]
    const unsigned short* __restrict__ Wob,  // [E][E]
    float* __restrict__ out)                 // [M][E] fp32
{
    __shared__ unsigned short As[128*64];
    __shared__ unsigned short Bs[128*64];
    const int tid = threadIdx.x;
    const int w = tid >> 6, lane = tid & 63, quad = lane >> 4, col = lane & 15;
    const int wm = (w & 1) * 64, wn = (w >> 1) * 64;
    const int m0 = blockIdx.x * 128, n0 = blockIdx.y * 128;
    const int srow = lane >> 3, schunk = (lane & 7) * 8;

    f32x4 acc[4][4] = {};
    for (int k0 = 0; k0 < E_; k0 += 64) {
        #pragma unroll
        for (int c = 0; c < 4; c++) {
            int row = w*32 + c*8 + srow;
            gload_lds16(&ctx[(size_t)(m0+row)*E_ + k0 + schunk], &As[(w*32 + c*8)*64]);
            gload_lds16(&Wob[(size_t)(n0+row)*E_ + k0 + schunk], &Bs[(w*32 + c*8)*64]);
        }
        __syncthreads();
        #pragma unroll
        for (int kk = 0; kk < 64; kk += 32) {
            short8 a[4], b[4];
            #pragma unroll
            for (int i = 0; i < 4; i++)
                a[i] = *(const short8*)&As[(wm + i*16 + col)*64 + kk + quad*8];
            #pragma unroll
            for (int j = 0; j < 4; j++)
                b[j] = *(const short8*)&Bs[(wn + j*16 + col)*64 + kk + quad*8];
            #pragma unroll
            for (int i = 0; i < 4; i++)
                #pragma unroll
                for (int j = 0; j < 4; j++)
                    acc[i][j] = __builtin_amdgcn_mfma_f32_16x16x32_bf16(a[i], b[j], acc[i][j], 0, 0, 0);
        }
        __syncthreads();
    }
    #pragma unroll
    for (int j = 0; j < 4; j++) {
        int n = n0 + wn + j*16 + col;
        #pragma unroll
        for (int i = 0; i < 4; i++)
            #pragma unroll
            for (int r = 0; r < 4; r++) {
                int m = m0 + wm + i*16 + quad*4 + r;
                out[(size_t)m*E_ + n] = acc[i][j][r];
            }
    }
}

// ---------------------------------------------------------------------------
// Flash attention (round-5 structure, verbatim except v_perm pack):
// S^T formulation, 32x32x16 MFMA, C->A transform via up-front shfl_xor pp[],
// l computed by MFMA with an all-ones B fragment, p=exp2(score) (Q pre-scaled).
// ---------------------------------------------------------------------------
#define LPK 72   // padded LDS row stride (elements)

__global__ __launch_bounds__(256, 4) void flash_attn(
    const unsigned short* __restrict__ qb,   // pre-scaled by QSCALE
    const unsigned short* __restrict__ kb,
    const unsigned short* __restrict__ vtb,
    unsigned short* __restrict__ ctx)        // [M][E] bf16
{
    __shared__ unsigned short Kt[64*LPK];    // [key][d]
    __shared__ unsigned short Vt[64*LPK];    // [d][key]
    const int tid = threadIdx.x;
    const int w = tid >> 6, lane = tid & 63, col = lane & 31, half = lane >> 5;
    const int q0 = blockIdx.x * 128;
    const int bh = blockIdx.y;

    short8 qf[4];
    {
        const unsigned short* qrow = qb + ((size_t)bh*S_ + q0 + w*32 + col)*DK_;
        #pragma unroll
        for (int c = 0; c < 4; c++)
            qf[c] = *(const short8*)&qrow[c*16 + half*8];
    }

    union U8 { unsigned u[4]; short8 s8; };
    U8 ones;
    #pragma unroll
    for (int i = 0; i < 4; i++) ones.u[i] = 0x3F803F80u;   // bf16 1.0 pair

    f32x16 oacc[2] = {};
    f32x16 lacc = {};

    for (int kt = 0; kt < S_; kt += 64) {
        __syncthreads();
        for (int i = tid; i < 512; i += 256) {
            int row = i >> 3, c8 = (i & 7) * 8;
            *(int4*)&Kt[row*LPK + c8] = *(const int4*)&kb [((size_t)bh*S_  + kt + row)*DK_ + c8];
            *(int4*)&Vt[row*LPK + c8] = *(const int4*)&vtb[((size_t)bh*DK_ + row)*S_ + kt + c8];
        }
        __syncthreads();

        #pragma unroll
        for (int t = 0; t < 2; t++) {
            // S^T = K.Q^T over this 32-key tile
            f32x16 sacc = {};
            #pragma unroll
            for (int c = 0; c < 4; c++) {
                short8 kf = *(const short8*)&Kt[(t*32 + col)*LPK + c*16 + half*8];
                sacc = __builtin_amdgcn_mfma_f32_32x32x16_bf16(kf, qf[c], sacc, 0, 0, 0);
            }
            // p = exp2(score); pack pairs via v_perm (hi-16 truncation)
            unsigned pk[4][2], pp[4][2];
            #pragma unroll
            for (int rg = 0; rg < 4; rg++) {
                float p0 = __builtin_amdgcn_exp2f(sacc[rg*4+0]);
                float p1 = __builtin_amdgcn_exp2f(sacc[rg*4+1]);
                float p2 = __builtin_amdgcn_exp2f(sacc[rg*4+2]);
                float p3 = __builtin_amdgcn_exp2f(sacc[rg*4+3]);
                pk[rg][0] = __builtin_amdgcn_perm(__float_as_uint(p1), __float_as_uint(p0), 0x07060302u);
                pk[rg][1] = __builtin_amdgcn_perm(__float_as_uint(p3), __float_as_uint(p2), 0x07060302u);
            }
            #pragma unroll
            for (int rg = 0; rg < 4; rg++) {
                pp[rg][0] = __shfl_xor((int)pk[rg][0], 32);
                pp[rg][1] = __shfl_xor((int)pk[rg][1], 32);
            }
            // PV + l over the two 16-key chunks of this tile
            #pragma unroll
            for (int kc = 0; kc < 2; kc++) {
                const int lo = 2*kc, hi = 2*kc + 1;
                U8 pa;
                pa.u[0] = half ? pp[hi][0] : pk[lo][0];
                pa.u[1] = half ? pp[hi][1] : pk[lo][1];
                pa.u[2] = half ? pk[hi][0] : pp[lo][0];
                pa.u[3] = half ? pk[hi][1] : pp[lo][1];
                lacc = __builtin_amdgcn_mfma_f32_32x32x16_bf16(pa.s8, ones.s8, lacc, 0, 0, 0);
                #pragma unroll
                for (int dt = 0; dt < 2; dt++) {
                    short8 vf = *(const short8*)&Vt[(dt*32 + col)*LPK + t*32 + kc*16 + half*8];
                    oacc[dt] = __builtin_amdgcn_mfma_f32_32x32x16_bf16(pa.s8, vf, oacc[dt], 0, 0, 0);
                }
            }
        }
    }

    // epilogue: lacc rows match oacc rows exactly (C row = rr + 8*rg + 4*half)
    const int b = bh >> 4, h = bh & 15;
    #pragma unroll
    for (int rg = 0; rg < 4; rg++)
        #pragma unroll
        for (int rr = 0; rr < 4; rr++) {
            int row = rr + rg*8 + half*4;
            float inv = 1.0f / lacc[rg*4 + rr];
            int s = q0 + w*32 + row;
            size_t rowoff = ((size_t)(b*S_ + s))*E_ + h*64;
            #pragma unroll
            for (int dt = 0; dt < 2; dt++)
                ctx[rowoff + dt*32 + col] = f2b(oacc[dt][rg*4 + rr] * inv);
        }
}

extern "C" void kernel_launch(void* const* d_in, const int* in_sizes, int n_in,
                              void* d_out, int out_size, void* d_ws, size_t ws_size,
                              hipStream_t stream) {
    (void)in_sizes; (void)n_in; (void)out_size; (void)ws_size;
    const float* x     = (const float*)d_in[0];
    const float* Wq    = (const float*)d_in[1];
    const float* Wk    = (const float*)d_in[2];
    const float* Wv    = (const float*)d_in[3];
    const float* Wo    = (const float*)d_in[4];
    const float* theta = (const float*)d_in[5];
    float* out = (float*)d_out;

    unsigned short* ws  = (unsigned short*)d_ws;
    unsigned short* xb  = ws;                                    // M*E
    unsigned short* Wb  = xb  + (size_t)M_*E_;                   // 3*E*E
    unsigned short* Wob = Wb  + (size_t)3*E_*E_;                 // E*E
    unsigned short* qb  = Wob + (size_t)E_*E_;
    unsigned short* kb  = qb  + (size_t)B_*H_*S_*DK_;
    unsigned short* vtb = kb  + (size_t)B_*H_*S_*DK_;
    unsigned short* ctx = xb;                                    // alias (xb dead after gemm_qkv)

    cvt_all<<<(XN4 + 4*WN4)/256, 256, 0, stream>>>(x, Wq, Wk, Wv, Wo, xb, Wb, Wob);

    gemm_qkv<<<dim3(M_/128, E_/128, 3), 256, 0, stream>>>(xb, Wb, theta, qb, kb, vtb);
    flash_attn<<<dim3(S_/128, B_*H_), 256, 0, stream>>>(qb, kb, vtb, ctx);
    gemm_out<<<dim3(M_/128, E_/128), 256, 0, stream>>>(ctx, Wob, out);
}